// Round 1
// 528.146 us; speedup vs baseline: 1.0308x; 1.0308x over previous
//
#include <hip/hip_runtime.h>
#include <hip/hip_bf16.h>
#include <math.h>
#include <stdint.h>

#define BT  4096
#define DIM 1024
#define HID 4096
#define NE  8
#define TMX  72   // max active 128-row m-blocks (64 full + 8 partial)
#define TMX2 40   // max active 256-row m-blocks (32 full + 8 partial)

typedef __attribute__((ext_vector_type(8))) short short8v;
typedef __attribute__((ext_vector_type(4))) float f32x4;
typedef unsigned short ushort_t;

typedef __attribute__((address_space(1))) const void gas_void;
typedef __attribute__((address_space(3))) void las_void;
#define GLOAD_LDS16(g, l) __builtin_amdgcn_global_load_lds((gas_void*)(g), (las_void*)(l), 16, 0, 0)

__device__ inline ushort_t f2bf(float f) {
  __hip_bfloat16 b = __float2bfloat16(f);
  union { __hip_bfloat16 h; ushort_t u; } cv;
  cv.h = b;
  return cv.u;
}

// -------- prep: x fp32 -> bf16 ; zero per-expert cursors --------
__global__ void k_prep_x(const float* __restrict__ x, ushort_t* __restrict__ xbf,
                         int* __restrict__ cur) {
  if (blockIdx.x == 0 && threadIdx.x < NE) cur[threadIdx.x] = 0;
  int idx = blockIdx.x * blockDim.x + threadIdx.x;
  const int n4 = BT * DIM / 4;
  for (int i = idx; i < n4; i += gridDim.x * blockDim.x) {
    float4 v = ((const float4*)x)[i];
    ushort4 o;
    o.x = f2bf(v.x); o.y = f2bf(v.y); o.z = f2bf(v.z); o.w = f2bf(v.w);
    ((ushort4*)xbf)[i] = o;
  }
}

// -------- transpose+convert: src fp32 [E][R][C] -> dst bf16 [E][C][R] --------
__global__ __launch_bounds__(256) void k_transpose(const float* __restrict__ src,
                                                   ushort_t* __restrict__ dst,
                                                   int R, int C) {
  __shared__ float tile[64][65];
  int e = blockIdx.z;
  const float* s = src + (size_t)e * R * C;
  ushort_t* d = dst + (size_t)e * R * C;
  int c0 = blockIdx.x * 64, r0 = blockIdx.y * 64;
  int t = threadIdx.x;
  int lr = t >> 4;
  int lc4 = (t & 15) * 4;
#pragma unroll
  for (int i = 0; i < 4; i++) {
    int r = lr + 16 * i;
    float4 v = *(const float4*)&s[(size_t)(r0 + r) * C + c0 + lc4];
    tile[r][lc4 + 0] = v.x; tile[r][lc4 + 1] = v.y;
    tile[r][lc4 + 2] = v.z; tile[r][lc4 + 3] = v.w;
  }
  __syncthreads();
#pragma unroll
  for (int i = 0; i < 4; i++) {
    int c = lr + 16 * i;
    ushort4 o;
    o.x = f2bf(tile[lc4 + 0][c]);
    o.y = f2bf(tile[lc4 + 1][c]);
    o.z = f2bf(tile[lc4 + 2][c]);
    o.w = f2bf(tile[lc4 + 3][c]);
    *(ushort4*)&d[(size_t)(c0 + c) * R + r0 + lc4] = o;
  }
}

// -------- router: logits, softmax, top-2, binning --------
__global__ __launch_bounds__(64) void k_router(
    const float* __restrict__ x, const float* __restrict__ wg,
    float* __restrict__ logits_out, float* __restrict__ probs01,
    int* __restrict__ assign, int* __restrict__ cur) {
  int t = blockIdx.x;
  int lane = threadIdx.x;
  float part[NE];
#pragma unroll
  for (int e = 0; e < NE; e++) part[e] = 0.f;
  const float* xr = x + (size_t)t * DIM;
  for (int d = lane; d < DIM; d += 64) {
    float xv = xr[d];
    const float4* wr = (const float4*)(wg + (size_t)d * NE);
    float4 w0 = wr[0], w1v = wr[1];
    part[0] += xv * w0.x;  part[1] += xv * w0.y;
    part[2] += xv * w0.z;  part[3] += xv * w0.w;
    part[4] += xv * w1v.x; part[5] += xv * w1v.y;
    part[6] += xv * w1v.z; part[7] += xv * w1v.w;
  }
#pragma unroll
  for (int e = 0; e < NE; e++)
    for (int off = 32; off > 0; off >>= 1)
      part[e] += __shfl_xor(part[e], off);
  if (lane == 0) {
    float m = part[0];
    for (int e = 1; e < NE; e++) m = fmaxf(m, part[e]);
    float p[NE], s = 0.f;
    for (int e = 0; e < NE; e++) { p[e] = expf(part[e] - m); s += p[e]; }
    float inv = 1.f / s;
    for (int e = 0; e < NE; e++) p[e] *= inv;
    for (int e = 0; e < NE; e++) logits_out[(size_t)t * NE + e] = part[e];
    probs01[t * 2 + 0] = p[0];
    probs01[t * 2 + 1] = p[1];
    int b0 = 0;
    for (int e = 1; e < NE; e++) if (p[e] > p[b0]) b0 = e;
    int b1 = (b0 == 0) ? 1 : 0;
    for (int e = 0; e < NE; e++) if (e != b0 && p[e] > p[b1]) b1 = e;
    int pos0 = atomicAdd(&cur[b0], 1);
    assign[b0 * BT + pos0] = t * 2 + 0;
    int pos1 = atomicAdd(&cur[b1], 1);
    assign[b1 * BT + pos1] = t * 2 + 1;
  }
}

// -------- plan: prefix offsets + flattened active block lists (128 & 256) --------
__global__ void k_plan(const int* __restrict__ cur, int* __restrict__ segoff,
                       int* __restrict__ blk_e, int* __restrict__ blk_m0,
                       int* __restrict__ blk2_e, int* __restrict__ blk2_m0) {
  if (threadIdx.x == 0 && blockIdx.x == 0) {
    int s = 0;
    for (int e = 0; e < NE; e++) { segoff[e] = s; s += cur[e]; }
    int t = 0;
    for (int e = 0; e < NE; e++) {
      int mb = (cur[e] + 127) >> 7;
      for (int i = 0; i < mb; i++) { blk_e[t] = e; blk_m0[t] = i << 7; t++; }
    }
    for (; t < TMX; t++) { blk_e[t] = -1; blk_m0[t] = 0; }
    t = 0;
    for (int e = 0; e < NE; e++) {
      int mb = (cur[e] + 255) >> 8;
      for (int i = 0; i < mb; i++) { blk2_e[t] = e; blk2_m0[t] = i << 8; t++; }
    }
    for (; t < TMX2; t++) { blk2_e[t] = -1; blk2_m0[t] = 0; }
  }
}

// ============================================================================
// GEMM1: h = gelu(x_gathered @ w1^T + b1)
// 256x256 tile, BK=64, 8 waves (2x4), 128 KiB LDS dbuf, T2 XOR-swizzle.
// LDS logical (row, 16B-unit u) stored at unit u ^ (row&7); global_load_lds
// writes linearly so the per-lane SOURCE col is pre-swizzled with the same
// involution; ds_read applies the swizzle on the read side.
// ============================================================================
__global__ __launch_bounds__(512, 2) void k_gemm1(
    const ushort_t* __restrict__ xbf, const ushort_t* __restrict__ wt1,
    const float* __restrict__ b1,
    const int* __restrict__ assign, const int* __restrict__ cur,
    const int* __restrict__ segoff, const int* __restrict__ blk2_e,
    const int* __restrict__ blk2_m0, ushort_t* __restrict__ hbuf) {
  const int nwg = 16 * TMX2;                   // 640, divisible by 8
  int f = blockIdx.x;
  int lg = (f & 7) * (nwg >> 3) + (f >> 3);    // XCD chunk swizzle (bijective)
  int m_idx = lg % TMX2;                       // m-major inner: chunk = 2 B-panels
  int n_idx = lg / TMX2;
  int e = blk2_e[m_idx];
  if (e < 0) return;
  int m0 = blk2_m0[m_idx];
  int count = cur[e];
  int n0 = n_idx << 8;

  __shared__ __attribute__((aligned(16))) ushort_t A[2][256][64];
  __shared__ __attribute__((aligned(16))) ushort_t Bv[2][256][64];
  int tid = threadIdx.x;
  int lane = tid & 63, wid = tid >> 6;

  // staging: call c covers rows c*64 + wid*8 + (lane>>3); lane writes LDS
  // 16B-unit (lane&7) of its row, so source unit = (lane&7) ^ (lane>>3)
  int srow = wid * 8 + (lane >> 3);
  int scol = ((lane & 7) ^ (lane >> 3)) << 3;  // bf16 offset (units of 8)
  const ushort_t* gA[4];
  const ushort_t* gB[4];
#pragma unroll
  for (int c = 0; c < 4; c++) {
    int p = m0 + c * 64 + srow;
    int tok = (p < count) ? (assign[e * BT + p] >> 1) : 0;
    gA[c] = xbf + (size_t)tok * DIM + scol;
    gB[c] = wt1 + ((size_t)e * HID + n0 + c * 64 + srow) * DIM + scol;
  }

  int wm = wid >> 2, wn = wid & 3;             // wave tile: 128(m) x 64(n)
  int lr = lane & 15, g = lane >> 4;
  f32x4 acc[8][4];
  f32x4 zero = {0.f, 0.f, 0.f, 0.f};
#pragma unroll
  for (int m = 0; m < 8; m++)
#pragma unroll
    for (int n = 0; n < 4; n++) acc[m][n] = zero;

#define STAGE1(buf, k0)                                        \
  { GLOAD_LDS16(gA[0] + (k0), &A[buf][0 * 64 + wid * 8][0]);   \
    GLOAD_LDS16(gA[1] + (k0), &A[buf][1 * 64 + wid * 8][0]);   \
    GLOAD_LDS16(gA[2] + (k0), &A[buf][2 * 64 + wid * 8][0]);   \
    GLOAD_LDS16(gA[3] + (k0), &A[buf][3 * 64 + wid * 8][0]);   \
    GLOAD_LDS16(gB[0] + (k0), &Bv[buf][0 * 64 + wid * 8][0]);  \
    GLOAD_LDS16(gB[1] + (k0), &Bv[buf][1 * 64 + wid * 8][0]);  \
    GLOAD_LDS16(gB[2] + (k0), &Bv[buf][2 * 64 + wid * 8][0]);  \
    GLOAD_LDS16(gB[3] + (k0), &Bv[buf][3 * 64 + wid * 8][0]); }

#define COMPUTE1(buf)                                                              \
  { _Pragma("unroll")                                                              \
    for (int kk = 0; kk < 2; kk++) {                                               \
      short8v af[8], bfv[4];                                                       \
      _Pragma("unroll")                                                            \
      for (int m = 0; m < 8; m++)                                                  \
        af[m] = *(const short8v*)&A[buf][wm * 128 + m * 16 + lr]                   \
                                       [((kk * 4 + g) ^ (lr & 7)) << 3];           \
      _Pragma("unroll")                                                            \
      for (int n = 0; n < 4; n++)                                                  \
        bfv[n] = *(const short8v*)&Bv[buf][wn * 64 + n * 16 + lr]                  \
                                        [((kk * 4 + g) ^ (lr & 7)) << 3];          \
      _Pragma("unroll")                                                            \
      for (int m = 0; m < 8; m++)                                                  \
        _Pragma("unroll")                                                          \
        for (int n = 0; n < 4; n++)                                                \
          acc[m][n] = __builtin_amdgcn_mfma_f32_16x16x32_bf16(af[m], bfv[n],       \
                                                              acc[m][n], 0, 0, 0); \
    } }

  STAGE1(0, 0);
  __syncthreads();
  for (int k0 = 64; k0 < DIM - 64; k0 += 128) {
    STAGE1(1, k0);
    COMPUTE1(0);
    __syncthreads();
    STAGE1(0, k0 + 64);
    COMPUTE1(1);
    __syncthreads();
  }
  STAGE1(1, DIM - 64);
  COMPUTE1(0);
  __syncthreads();
  COMPUTE1(1);
#undef STAGE1
#undef COMPUTE1

  int so = segoff[e];
#pragma unroll
  for (int m = 0; m < 8; m++) {
#pragma unroll
    for (int j = 0; j < 4; j++) {
      int p = m0 + wm * 128 + m * 16 + g * 4 + j;
      if (p >= count) continue;
      ushort_t* hr = hbuf + (size_t)(so + p) * HID;
#pragma unroll
      for (int n = 0; n < 4; n++) {
        int col = n0 + wn * 64 + n * 16 + lr;
        float v = acc[m][n][j] + b1[e * HID + col];
        float gl = 0.5f * v * (1.0f + erff(v * 0.70710678118654752f));
        hr[col] = f2bf(gl);
      }
    }
  }
}

// ============================================================================
// GEMM2: contrib[slot][t] = h @ w2^T + b2
// 128x128 tile, BK=64, 8 waves (2x4, wave tile 64x32), 64 KiB LDS, 2 blk/CU.
// ============================================================================
__global__ __launch_bounds__(512, 4) void k_gemm2(
    const ushort_t* __restrict__ hbuf, const ushort_t* __restrict__ wt2,
    const float* __restrict__ b2,
    const int* __restrict__ assign, const int* __restrict__ cur,
    const int* __restrict__ segoff, const int* __restrict__ blk_e,
    const int* __restrict__ blk_m0, float* __restrict__ contrib) {
  const int nwg = 8 * TMX;                     // 576, divisible by 8
  int f = blockIdx.x;
  int lg = (f & 7) * (nwg >> 3) + (f >> 3);
  int m_idx = lg % TMX;                        // m-major inner: chunk = 1 B-panel
  int n_idx = lg / TMX;
  int e = blk_e[m_idx];
  if (e < 0) return;
  int m0 = blk_m0[m_idx];
  int count = cur[e];
  int n0 = n_idx << 7;
  int so = segoff[e];

  __shared__ __attribute__((aligned(16))) ushort_t A[2][128][64];
  __shared__ __attribute__((aligned(16))) ushort_t Bv[2][128][64];
  int tid = threadIdx.x;
  int lane = tid & 63, wid = tid >> 6;

  int srow = wid * 8 + (lane >> 3);
  int scol = ((lane & 7) ^ (lane >> 3)) << 3;
  const ushort_t* gA[2];
  const ushort_t* gB[2];
#pragma unroll
  for (int c = 0; c < 2; c++) {
    int p = m0 + c * 64 + srow;
    int pa = (p < count) ? p : (count - 1);
    gA[c] = hbuf + (size_t)(so + pa) * HID + scol;
    gB[c] = wt2 + ((size_t)e * DIM + n0 + c * 64 + srow) * HID + scol;
  }

  int wm = wid >> 2, wn = wid & 3;             // wave tile: 64(m) x 32(n)
  int lr = lane & 15, g = lane >> 4;
  f32x4 acc[4][2];
  f32x4 zero = {0.f, 0.f, 0.f, 0.f};
#pragma unroll
  for (int m = 0; m < 4; m++)
#pragma unroll
    for (int n = 0; n < 2; n++) acc[m][n] = zero;

#define STAGE2(buf, k0)                                        \
  { GLOAD_LDS16(gA[0] + (k0), &A[buf][0 * 64 + wid * 8][0]);   \
    GLOAD_LDS16(gA[1] + (k0), &A[buf][1 * 64 + wid * 8][0]);   \
    GLOAD_LDS16(gB[0] + (k0), &Bv[buf][0 * 64 + wid * 8][0]);  \
    GLOAD_LDS16(gB[1] + (k0), &Bv[buf][1 * 64 + wid * 8][0]); }

#define COMPUTE2(buf)                                                              \
  { _Pragma("unroll")                                                              \
    for (int kk = 0; kk < 2; kk++) {                                               \
      short8v af[4], bfv[2];                                                       \
      _Pragma("unroll")                                                            \
      for (int m = 0; m < 4; m++)                                                  \
        af[m] = *(const short8v*)&A[buf][wm * 64 + m * 16 + lr]                    \
                                       [((kk * 4 + g) ^ (lr & 7)) << 3];           \
      _Pragma("unroll")                                                            \
      for (int n = 0; n < 2; n++)                                                  \
        bfv[n] = *(const short8v*)&Bv[buf][wn * 32 + n * 16 + lr]                  \
                                        [((kk * 4 + g) ^ (lr & 7)) << 3];          \
      _Pragma("unroll")                                                            \
      for (int m = 0; m < 4; m++)                                                  \
        _Pragma("unroll")                                                          \
        for (int n = 0; n < 2; n++)                                                \
          acc[m][n] = __builtin_amdgcn_mfma_f32_16x16x32_bf16(af[m], bfv[n],       \
                                                              acc[m][n], 0, 0, 0); \
    } }

  STAGE2(0, 0);
  __syncthreads();
  for (int k0 = 64; k0 < HID - 64; k0 += 128) {
    STAGE2(1, k0);
    COMPUTE2(0);
    __syncthreads();
    STAGE2(0, k0 + 64);
    COMPUTE2(1);
    __syncthreads();
  }
  STAGE2(1, HID - 64);
  COMPUTE2(0);
  __syncthreads();
  COMPUTE2(1);
#undef STAGE2
#undef COMPUTE2

#pragma unroll
  for (int m = 0; m < 4; m++) {
#pragma unroll
    for (int j = 0; j < 4; j++) {
      int p = m0 + wm * 64 + m * 16 + g * 4 + j;
      if (p >= count) continue;
      int a = assign[e * BT + p];
      int t = a >> 1, slot = a & 1;
      float* cr = contrib + ((size_t)slot * BT + t) * DIM;
#pragma unroll
      for (int n = 0; n < 2; n++) {
        int col = n0 + wn * 32 + n * 16 + lr;
        cr[col] = acc[m][n][j] + b2[e * DIM + col];
      }
    }
  }
}

// -------- combine: final = c0*probs[:,0] + c1*probs[:,1] --------
__global__ void k_combine(const float* __restrict__ contrib,
                          const float* __restrict__ probs01,
                          float* __restrict__ out) {
  int idx = blockIdx.x * blockDim.x + threadIdx.x;
  const int n4 = BT * DIM / 4;
  if (idx >= n4) return;
  int t = idx >> 8;
  float wA = probs01[t * 2 + 0], wB = probs01[t * 2 + 1];
  float4 c0 = ((const float4*)contrib)[idx];
  float4 c1 = ((const float4*)(contrib + (size_t)BT * DIM))[idx];
  float4 o;
  o.x = c0.x * wA + c1.x * wB;
  o.y = c0.y * wA + c1.y * wB;
  o.z = c0.z * wA + c1.z * wB;
  o.w = c0.w * wA + c1.w * wB;
  ((float4*)out)[idx] = o;
}

extern "C" void kernel_launch(void* const* d_in, const int* in_sizes, int n_in,
                              void* d_out, int out_size, void* d_ws, size_t ws_size,
                              hipStream_t stream) {
  const float* x  = (const float*)d_in[0];
  const float* wg = (const float*)d_in[1];
  const float* w1 = (const float*)d_in[2];
  const float* b1 = (const float*)d_in[3];
  const float* w2 = (const float*)d_in[4];
  const float* b2 = (const float*)d_in[5];
  float* out = (float*)d_out;
  float* logits_out = out + (size_t)BT * DIM;

  char* ws = (char*)d_ws;
  size_t off = 0;
  auto alloc = [&](size_t bytes) -> void* {
    void* p = ws + off;
    off = (off + bytes + 255) & ~(size_t)255;
    return p;
  };
  ushort_t* xbf    = (ushort_t*)alloc((size_t)BT * DIM * 2);
  ushort_t* wt1    = (ushort_t*)alloc((size_t)NE * HID * DIM * 2);
  ushort_t* wt2    = (ushort_t*)alloc((size_t)NE * DIM * HID * 2);
  ushort_t* hbuf   = (ushort_t*)alloc((size_t)2 * BT * HID * 2);
  float*    contrib= (float*)alloc((size_t)2 * BT * DIM * 4);
  float*    probs01= (float*)alloc((size_t)BT * 2 * 4);
  int*      assign = (int*)alloc((size_t)NE * BT * 4);
  int*      cur    = (int*)alloc(64);
  int*      segoff = (int*)alloc(64);
  int*      blk_e  = (int*)alloc(TMX * 4);
  int*      blk_m0 = (int*)alloc(TMX * 4);
  int*      blk2_e = (int*)alloc(TMX2 * 4);
  int*      blk2_m0= (int*)alloc(TMX2 * 4);
  if (off > ws_size) return;

  hipLaunchKernelGGL(k_prep_x, dim3(1024), dim3(256), 0, stream, x, xbf, cur);
  hipLaunchKernelGGL(k_transpose, dim3(HID / 64, DIM / 64, NE), dim3(256), 0, stream,
                     w1, wt1, DIM, HID);
  hipLaunchKernelGGL(k_transpose, dim3(DIM / 64, HID / 64, NE), dim3(256), 0, stream,
                     w2, wt2, HID, DIM);
  hipLaunchKernelGGL(k_router, dim3(BT), dim3(64), 0, stream,
                     x, wg, logits_out, probs01, assign, cur);
  hipLaunchKernelGGL(k_plan, dim3(1), dim3(1), 0, stream, cur, segoff,
                     blk_e, blk_m0, blk2_e, blk2_m0);
  hipLaunchKernelGGL(k_gemm1, dim3(16 * TMX2), dim3(512), 0, stream,
                     xbf, wt1, b1, assign, cur, segoff, blk2_e, blk2_m0, hbuf);
  hipLaunchKernelGGL(k_gemm2, dim3(8 * TMX), dim3(512), 0, stream,
                     hbuf, wt2, b2, assign, cur, segoff, blk_e, blk_m0, contrib);
  hipLaunchKernelGGL(k_combine, dim3((BT * DIM / 4 + 255) / 256), dim3(256), 0, stream,
                     contrib, probs01, out);
}